// Round 9
// baseline (3222.694 us; speedup 1.0000x reference)
//
#include <hip/hip_runtime.h>
#include <math.h>
#include <float.h>

namespace {

constexpr int Bb = 8, Kk = 4, BKn = 32, Dd = 1024, Ff = 4096, Vv = 32000, Tt = 16;
constexpr int GDS = 32, GDC = 32;        // gates d-split / d-chunk  (32*32 = 1024)
constexpr int LTW = 32;                  // logits cols per tile
constexpr int LNB = Vv / LTW;            // 1000 blocks
constexpr int LCH = 64;                  // d per chunk
constexpr int LNCH = Dd / LCH;           // 16 chunks
constexpr int NVCH = LNB;                // 1000 chunk-stat rows
constexpr int EOSt = 2, PADt = 0;
constexpr float BIGf = 1e9f, EOSSf = 1000.0f;

// ---- workspace layout (float indices) ----
constexpr size_t OFF_HTN = 0;                                   // hTn [1024][32]
constexpr size_t OFF_CB0 = OFF_HTN + (size_t)Dd * BKn;          // c ping [32][1024]
constexpr size_t OFF_CB1 = OFF_CB0 + (size_t)BKn * Dd;          // c pong
constexpr size_t OFF_GP  = OFF_CB1 + (size_t)BKn * Dd;          // gate partials [32][32][4096]
constexpr size_t OFF_CS  = OFF_GP  + (size_t)GDS * BKn * Ff;    // chunk stats [1000][32][12]
constexpr size_t OFF_SC  = OFF_CS  + (size_t)NVCH * BKn * 12;   // scores [32]
constexpr size_t OFF_INT = OFF_SC  + BKn;                       // int region
constexpr int IW = 0, ISTOP = 32, IPREV = 40, IBUFA = 72, IBUFB = IBUFA + Bb * Kk * Tt;

__device__ __forceinline__ void cp16(const float* g, float* l) {
  __builtin_amdgcn_global_load_lds(
      (const __attribute__((address_space(1))) void*)g,
      (__attribute__((address_space(3))) void*)l, 16, 0, 0);
}

__device__ inline void ins4(float v, int id, float tv[4], int ti[4]) {
#pragma unroll
  for (int r = 0; r < 4; r++) {
    bool better = (v > tv[r]) || (v == tv[r] && id < ti[r]);
    if (better) { float fv = tv[r]; int fi = ti[r]; tv[r] = v; ti[r] = id; v = fv; id = fi; }
  }
}

// merge per-lane sorted top-4 into group-global top-4. STARTOFF=32 -> 64-lane wave,
// STARTOFF=16 -> independent 32-lane halves.
template <int STARTOFF>
__device__ inline void merge_top4(float tv[4], int ti[4], float ov[4], int oi[4]) {
#pragma unroll
  for (int r = 0; r < 4; r++) {
    float hv = tv[0]; int hi = ti[0];
    float m = hv;
    for (int off = STARTOFF; off; off >>= 1) m = fmaxf(m, __shfl_xor(m, off));
    int c = (hv == m) ? hi : 0x7fffffff;
    for (int off = STARTOFF; off; off >>= 1) c = min(c, __shfl_xor(c, off));
    if (hv == m && hi == c) {   // this lane's head won: pop
      tv[0] = tv[1]; ti[0] = ti[1];
      tv[1] = tv[2]; ti[1] = ti[2];
      tv[2] = tv[3]; ti[2] = ti[3];
      tv[3] = -FLT_MAX; ti[3] = 0x7fffffff;
    }
    ov[r] = m; oi[r] = c;
  }
}

__global__ __launch_bounds__(256) void initK(const int* __restrict__ words,
    const float* __restrict__ h0, const float* __restrict__ c0,
    float* __restrict__ ws) {
  int* wsi = (int*)(ws + OFF_INT);
  if (blockIdx.x < 128) {
    int g = blockIdx.x * 256 + threadIdx.x;   // 0..32767
    int d = g >> 5, bk = g & 31;
    ws[OFF_HTN + g] = h0[(size_t)bk * Dd + d];   // transpose to [d][bk]
    ws[OFF_CB0 + g] = c0[g];                     // [32][1024] linear
  } else {
    int t = threadIdx.x;
    if (t < BKn) {
      ws[OFF_SC + t] = ((t & 3) == 0) ? 0.f : BIGf;
      wsi[IW + t] = words[t];
      wsi[IPREV + t] = t & 3;                    // identity gather for step 0
    }
    if (t < Bb) wsi[ISTOP + t] = 0;
    for (int i = t; i < 2 * Bb * Kk * Tt; i += 256) wsi[IBUFA + i] = 0;
  }
}

// gates partial GEMM. grid (32, 32): x = 128-col tile of f, y = d-chunk of 32.
__global__ __launch_bounds__(256) void gatesK(const float* __restrict__ Wx,
    const float* __restrict__ Wh, const float* __restrict__ E,
    const float* __restrict__ hTn, const int* __restrict__ wsi,
    float* __restrict__ Gp) {
  __shared__ float xs[GDC][BKn], hs[GDC][BKn];
  int tid = threadIdx.x;
  int d0 = blockIdx.y * GDC;
  {
    int bk = tid & 31, dq = tid >> 5;           // dq 0..7, 4 d each
    int w = wsi[IW + bk];
    int src = (bk & ~3) | wsi[IPREV + bk];
    const float* Erow = E + (size_t)w * Dd + d0;
#pragma unroll
    for (int k = 0; k < 4; k++) {
      int d = dq * 4 + k;
      xs[d][bk] = Erow[d];
      hs[d][bk] = hTn[(size_t)(d0 + d) * BKn + src];
    }
  }
  __syncthreads();
  int ct = tid & 31, bg = tid >> 5;             // 32 col-threads, 8 beam-groups
  int f0 = blockIdx.x * 128 + ct * 4;
  float acc[4][4];                               // [col][beam-in-group]
#pragma unroll
  for (int c = 0; c < 4; c++)
#pragma unroll
    for (int i = 0; i < 4; i++) acc[c][i] = 0.f;
#pragma unroll 4
  for (int d = 0; d < GDC; ++d) {
    float4 wx = *(const float4*)(Wx + (size_t)(d0 + d) * Ff + f0);
    float4 wh = *(const float4*)(Wh + (size_t)(d0 + d) * Ff + f0);
    float4 x4 = *(const float4*)&xs[d][bg * 4];
    float4 h4 = *(const float4*)&hs[d][bg * 4];
    float xv[4] = {x4.x, x4.y, x4.z, x4.w};
    float hv[4] = {h4.x, h4.y, h4.z, h4.w};
    float wxc[4] = {wx.x, wx.y, wx.z, wx.w};
    float whc[4] = {wh.x, wh.y, wh.z, wh.w};
#pragma unroll
    for (int c = 0; c < 4; c++)
#pragma unroll
      for (int i = 0; i < 4; i++)
        acc[c][i] = fmaf(xv[i], wxc[c], fmaf(hv[i], whc[c], acc[c][i]));
  }
#pragma unroll
  for (int i = 0; i < 4; i++) {
    int bk = bg * 4 + i;
    float4 o = {acc[0][i], acc[1][i], acc[2][i], acc[3][i]};
    *(float4*)(Gp + ((size_t)blockIdx.y * BKn + bk) * Ff + f0) = o;
  }
}

// reduce 32 gate partials + bias -> nonlinearity; gathers c by prev.
__global__ __launch_bounds__(256) void lstmK(const float* __restrict__ bvec,
    const float* __restrict__ Gp, const float* __restrict__ cPrev,
    const int* __restrict__ wsi, float* __restrict__ cNew,
    float* __restrict__ hTn) {
  __shared__ float part[4][128];
  int bk = blockIdx.x;
  int dcl = threadIdx.x & 127;
  int half = threadIdx.x >> 7;
  int dc = blockIdx.y * 128 + dcl;
  float s[4] = {0.f, 0.f, 0.f, 0.f};
#pragma unroll 4
  for (int dsl = 0; dsl < 16; dsl++) {
    int ds = half * 16 + dsl;
    const float* row = Gp + ((size_t)ds * BKn + bk) * Ff;
#pragma unroll
    for (int g = 0; g < 4; g++) s[g] += row[(size_t)g * Dd + dc];
  }
  if (half == 1) {
#pragma unroll
    for (int g = 0; g < 4; g++) part[g][dcl] = s[g];
  }
  __syncthreads();
  if (half == 0) {
    float gi = s[0] + part[0][dcl] + bvec[dc];
    float gf = s[1] + part[1][dcl] + bvec[Dd + dc];
    float gg = s[2] + part[2][dcl] + bvec[2 * Dd + dc];
    float go = s[3] + part[3][dcl] + bvec[3 * Dd + dc];
    int src = (bk & ~3) | wsi[IPREV + bk];
    float c = cPrev[(size_t)src * Dd + dc];
    float si = 1.f / (1.f + expf(-gi));
    float sf = 1.f / (1.f + expf(-gf));
    float so = 1.f / (1.f + expf(-go));
    float tg = tanhf(gg);
    float cn = sf * c + si * tg;
    float hn = so * tanhf(cn);
    cNew[(size_t)bk * Dd + dc] = cn;
    hTn[(size_t)dc * BKn + bk] = hn;
  }
}

// Async-staged full-depth logits + chunk stats. grid 1000 blocks x 256 thr.
// Block = 32 vocab cols x all 1024 d. Per 64-d chunk: DMA-stage Wo tile (8KB)
// + h chunk (8KB) into double-buffered LDS via global_load_lds (4 issues/wave),
// counted s_waitcnt vmcnt(4) + raw s_barrier (loads stay in flight across
// barriers -> deep MLP). FMA entirely from LDS. Then bias + stats -> cs.
__global__ __launch_bounds__(256) void logitsAK(const float* __restrict__ Wo,
    const float* __restrict__ bo, const float* __restrict__ hTn,
    float* __restrict__ cs) {
  __shared__ float wb[2][LCH][LTW];   // 16 KB
  __shared__ float hb[2][LCH][BKn];   // 16 KB
  __shared__ float sd[BKn][LTW];      // 4 KB
  int tid = threadIdx.x;
  int lane = tid & 63, wid = tid >> 6;
  int ct = tid & 7, bg = tid >> 3;    // 8 col-threads x 32 beams (1 beam each)
  size_t v0 = (size_t)blockIdx.x * LTW;
  float acc[4] = {0.f, 0.f, 0.f, 0.f};

  // bias load BEFORE the counted region (oldest outstanding, drains first)
  float4 b4 = *(const float4*)(bo + v0 + ct * 4);

#define STAGE(CH, B)                                                         \
  {                                                                          \
    int d0_ = (CH) * LCH;                                                    \
    _Pragma("unroll") for (int i_ = 0; i_ < 2; i_++) {                       \
      int r_ = i_ * 32 + wid * 8;                                            \
      cp16(Wo + (size_t)(d0_ + r_ + (lane >> 3)) * Vv + v0 + (lane & 7) * 4, \
           &wb[B][r_][0]);                                                   \
      cp16(hTn + (size_t)(d0_ + r_) * BKn + lane * 4, &hb[B][r_][0]);        \
    }                                                                        \
  }

  STAGE(0, 0)
  for (int ch = 0; ch < LNCH; ch++) {
    int b = ch & 1;
    if (ch + 1 < LNCH) {
      STAGE(ch + 1, b ^ 1)
      asm volatile("s_waitcnt vmcnt(4)" ::: "memory");  // chunk ch landed; ch+1 in flight
    } else {
      asm volatile("s_waitcnt vmcnt(0)" ::: "memory");
    }
    __builtin_amdgcn_s_barrier();
#pragma unroll 8
    for (int d = 0; d < LCH; d++) {
      float4 w4 = *(const float4*)&wb[b][d][ct * 4];
      float h = hb[b][d][bg];
      acc[0] = fmaf(w4.x, h, acc[0]);
      acc[1] = fmaf(w4.y, h, acc[1]);
      acc[2] = fmaf(w4.z, h, acc[2]);
      acc[3] = fmaf(w4.w, h, acc[3]);
    }
    __builtin_amdgcn_s_barrier();   // buf[b] free for overwrite next iter
  }
#undef STAGE

#pragma unroll
  for (int c = 0; c < 4; c++)
    sd[bg][ct * 4 + c] = acc[c] + ((const float*)&b4)[c];
  __syncthreads();

  // stats: 4 waves x (2 beams per 32-lane half x 4 iters) = 32 beams, 32 cols
  int l32 = lane & 31;
  int i0 = (int)v0 + l32;
  for (int bb_ = 0; bb_ < 4; ++bb_) {
    int bk = wid * 8 + bb_ * 2 + (lane >> 5);
    float v0f = sd[bk][l32];
    float m = v0f;
    for (int off = 16; off; off >>= 1) m = fmaxf(m, __shfl_xor(m, off));
    float se = expf(v0f - m);
    for (int off = 16; off; off >>= 1) se += __shfl_xor(se, off);
    float tv[4]; int ti[4];
#pragma unroll
    for (int r = 0; r < 4; r++) { tv[r] = -FLT_MAX; ti[r] = 0x7fffffff; }
    ins4(v0f, i0, tv, ti);
    float ov[4]; int oi[4];
    merge_top4<16>(tv, ti, ov, oi);
    if (l32 == 0) {
      float* p = cs + ((size_t)blockIdx.x * BKn + bk) * 12;
      p[0] = m; p[1] = se;
#pragma unroll
      for (int r = 0; r < 4; r++) { p[2 + r] = ov[r]; p[6 + r] = __int_as_float(oi[r]); }
    }
  }
}

// fused: per-beam online merge of 1000 chunk stats -> lse + top4; then exact
// selection, EOS logic, buf ping-pong. One block of 1024 threads.
__global__ __launch_bounds__(1024) void redSelK(float* __restrict__ ws, int step) {
  __shared__ float bt_s[BKn][8];
  __shared__ int s_tok[BKn], s_prevb[BKn];
  int* wsi = (int*)(ws + OFF_INT);
  const float* cs = ws + OFF_CS;
  int tid = threadIdx.x;
  int wv = tid >> 6, lane = tid & 63;
  {
    int half = lane >> 5, l32 = lane & 31;
    int bk = wv * 2 + half;                 // 16 waves x 2 halves = 32 beams
    float tv[4]; int ti[4];
#pragma unroll
    for (int r = 0; r < 4; r++) { tv[r] = -FLT_MAX; ti[r] = 0x7fffffff; }
    float M = -FLT_MAX, ls = 0.f;
    for (int q = 0; q < 32; q++) {
      int c = l32 + 32 * q;
      if (c < NVCH) {
        const float* p = cs + ((size_t)c * BKn + bk) * 12;
        float cm = p[0], csum = p[1];
        if (cm > M) { ls *= expf(M - cm); M = cm; }   // ls==0 when M==-inf
        ls += csum * expf(cm - M);
#pragma unroll
        for (int r = 0; r < 4; r++) ins4(p[2 + r], __float_as_int(p[6 + r]), tv, ti);
      }
    }
    for (int off = 16; off; off >>= 1) {
      float Mo = __shfl_xor(M, off), lso = __shfl_xor(ls, off);
      float Mn = fmaxf(M, Mo);
      ls = ls * expf(M - Mn) + lso * expf(Mo - Mn);
      M = Mn;
    }
    float lse = M + logf(ls);
    float ov[4]; int oi[4];
    merge_top4<16>(tv, ti, ov, oi);
    if (l32 == 0) {
#pragma unroll
      for (int r = 0; r < 4; r++) {
        bt_s[bk][r] = lse - ov[r];
        bt_s[bk][4 + r] = __int_as_float(oi[r]);
      }
    }
  }
  __syncthreads();
  if (tid < Bb) {
    int b = tid;
    int st = wsi[ISTOP + b];
    float sc[4];
#pragma unroll
    for (int k = 0; k < 4; k++) sc[k] = ws[OFF_SC + b * 4 + k];
    float cval[16]; int ctok[16];
#pragma unroll
    for (int kb = 0; kb < 4; kb++)
#pragma unroll
      for (int r = 0; r < 4; r++) {
        cval[kb * 4 + r] = bt_s[b * 4 + kb][r] + sc[kb];
        ctok[kb * 4 + r] = __float_as_int(bt_s[b * 4 + kb][4 + r]);
      }
    float selS[4]; int selW[4], prevK[4];
    int usedMask = 0;
#pragma unroll
    for (int r = 0; r < 4; r++) {
      int best = -1; float bv = FLT_MAX;
#pragma unroll
      for (int t = 0; t < 16; t++) {
        if (!((usedMask >> t) & 1) && cval[t] < bv) { bv = cval[t]; best = t; }
      }
      usedMask |= 1 << best;
      int tok = 0;
#pragma unroll
      for (int t = 0; t < 16; t++) if (t == best) tok = ctok[t];   // no runtime index
      selS[r] = bv; selW[r] = tok; prevK[r] = best >> 2;
    }
    bool eos[4];
#pragma unroll
    for (int r = 0; r < 4; r++) eos[r] = (selW[r] == EOSt);
    bool first = eos[0] && !st;
#pragma unroll
    for (int r = 0; r < 4; r++) if (eos[r] && !first && !st) selS[r] = EOSSf;
#pragma unroll
    for (int k = 0; k < 4; k++) {
      int tok = st ? PADt : (first ? EOSt : selW[k]);
      int pb  = st ? k : prevK[k];
      s_tok[b * 4 + k] = tok;
      s_prevb[b * 4 + k] = pb;
      if (!st) { ws[OFF_SC + b * 4 + k] = selS[k]; wsi[IW + b * 4 + k] = selW[k]; }
      wsi[IPREV + b * 4 + k] = prevK[k];
    }
    wsi[ISTOP + b] = (st || first) ? 1 : 0;
  }
  __syncthreads();
  if (tid < 512) {
    const int* br = wsi + (((step & 1) == 0) ? IBUFA : IBUFB);
    int* bw = wsi + (((step & 1) == 0) ? IBUFB : IBUFA);
    int bkk = tid >> 4, t = tid & 15;
    int pb = s_prevb[bkk];
    int src = ((bkk & ~3) | pb) * Tt + t;
    int val = br[src];
    if (t == step) val = s_tok[bkk];
    bw[tid] = val;
  }
}

// Output read as float32 by harness: tokens as float values, scores as floats.
__global__ __launch_bounds__(256) void outK(const float* __restrict__ ws,
                                            float* __restrict__ out) {
  const int* wsi = (const int*)(ws + OFF_INT);
  int g = blockIdx.x * 256 + threadIdx.x;
  if (g < Bb * Kk * Tt) {
    out[g] = (float)wsi[IBUFA + g];               // final buf in A after 16 steps
  } else if (g < Bb * Kk * Tt + BKn) {
    out[g] = ws[OFF_SC + (g - Bb * Kk * Tt)];
  }
}

} // namespace

extern "C" void kernel_launch(void* const* d_in, const int* in_sizes, int n_in,
                              void* d_out, int out_size, void* d_ws, size_t ws_size,
                              hipStream_t stream) {
  (void)in_sizes; (void)n_in; (void)out_size; (void)ws_size;
  const int*   words = (const int*)d_in[0];
  const float* h0 = (const float*)d_in[1];
  const float* c0 = (const float*)d_in[2];
  const float* E  = (const float*)d_in[3];
  const float* Wx = (const float*)d_in[4];
  const float* Wh = (const float*)d_in[5];
  const float* bv = (const float*)d_in[6];
  const float* Wo = (const float*)d_in[7];
  const float* bo = (const float*)d_in[8];
  float* ws = (float*)d_ws;
  float* hTn = ws + OFF_HTN;
  float* cb0 = ws + OFF_CB0;
  float* cb1 = ws + OFF_CB1;
  float* Gp  = ws + OFF_GP;
  float* cs  = ws + OFF_CS;
  int*   wsi = (int*)(ws + OFF_INT);

  initK<<<129, 256, 0, stream>>>(words, h0, c0, ws);
  for (int j = 0; j < Tt; j++) {
    float* cPrev = (j & 1) ? cb1 : cb0;
    float* cNext = (j & 1) ? cb0 : cb1;
    gatesK<<<dim3(32, GDS), 256, 0, stream>>>(Wx, Wh, E, hTn, wsi, Gp);
    lstmK<<<dim3(32, 8), 256, 0, stream>>>(bv, Gp, cPrev, wsi, cNext, hTn);
    logitsAK<<<LNB, 256, 0, stream>>>(Wo, bo, hTn, cs);
    redSelK<<<1, 1024, 0, stream>>>(ws, j);
  }
  outK<<<3, 256, 0, stream>>>(ws, (float*)d_out);
}

// Round 10
// 2423.197 us; speedup vs baseline: 1.3299x; 1.3299x over previous
//
#include <hip/hip_runtime.h>
#include <math.h>
#include <float.h>

namespace {

constexpr int Bb = 8, Kk = 4, BKn = 32, Dd = 1024, Ff = 4096, Vv = 32000, Tt = 16;
constexpr int GDS = 32, GDC = 32;        // gates d-split / d-chunk  (32*32 = 1024)
constexpr int LTW = 32;                  // logits cols per tile
constexpr int LNB = Vv / LTW;            // 1000 blocks
constexpr int LCH = 64;                  // d per chunk
constexpr int LNCH = Dd / LCH;           // 16 chunks
constexpr int NVCH = LNB;                // 1000 chunk-stat rows
constexpr int EOSt = 2, PADt = 0;
constexpr float BIGf = 1e9f, EOSSf = 1000.0f;

// ---- workspace layout (float indices) ----
constexpr size_t OFF_HTN = 0;                                   // hTn [1024][32]
constexpr size_t OFF_CB0 = OFF_HTN + (size_t)Dd * BKn;          // c ping [32][1024]
constexpr size_t OFF_CB1 = OFF_CB0 + (size_t)BKn * Dd;          // c pong
constexpr size_t OFF_GP  = OFF_CB1 + (size_t)BKn * Dd;          // gate partials [32][32][4096]
constexpr size_t OFF_CS  = OFF_GP  + (size_t)GDS * BKn * Ff;    // chunk stats [1000][32][12]
constexpr size_t OFF_SC  = OFF_CS  + (size_t)NVCH * BKn * 12;   // scores [32]
constexpr size_t OFF_INT = OFF_SC  + BKn;                       // int region
constexpr int IW = 0, ISTOP = 32, IPREV = 40, IBUFA = 72, IBUFB = IBUFA + Bb * Kk * Tt;

__device__ __forceinline__ void cp16(const float* g, float* l) {
  __builtin_amdgcn_global_load_lds(
      (const __attribute__((address_space(1))) void*)g,
      (__attribute__((address_space(3))) void*)l, 16, 0, 0);
}

__device__ inline void ins4(float v, int id, float tv[4], int ti[4]) {
#pragma unroll
  for (int r = 0; r < 4; r++) {
    bool better = (v > tv[r]) || (v == tv[r] && id < ti[r]);
    if (better) { float fv = tv[r]; int fi = ti[r]; tv[r] = v; ti[r] = id; v = fv; id = fi; }
  }
}

// merge per-lane sorted top-4 into group-global top-4. STARTOFF=32 -> 64-lane wave,
// STARTOFF=16 -> independent 32-lane halves.
template <int STARTOFF>
__device__ inline void merge_top4(float tv[4], int ti[4], float ov[4], int oi[4]) {
#pragma unroll
  for (int r = 0; r < 4; r++) {
    float hv = tv[0]; int hi = ti[0];
    float m = hv;
    for (int off = STARTOFF; off; off >>= 1) m = fmaxf(m, __shfl_xor(m, off));
    int c = (hv == m) ? hi : 0x7fffffff;
    for (int off = STARTOFF; off; off >>= 1) c = min(c, __shfl_xor(c, off));
    if (hv == m && hi == c) {   // this lane's head won: pop
      tv[0] = tv[1]; ti[0] = ti[1];
      tv[1] = tv[2]; ti[1] = ti[2];
      tv[2] = tv[3]; ti[2] = ti[3];
      tv[3] = -FLT_MAX; ti[3] = 0x7fffffff;
    }
    ov[r] = m; oi[r] = c;
  }
}

__global__ __launch_bounds__(256) void initK(const int* __restrict__ words,
    const float* __restrict__ h0, const float* __restrict__ c0,
    float* __restrict__ ws) {
  int* wsi = (int*)(ws + OFF_INT);
  if (blockIdx.x < 128) {
    int g = blockIdx.x * 256 + threadIdx.x;   // 0..32767
    int d = g >> 5, bk = g & 31;
    ws[OFF_HTN + g] = h0[(size_t)bk * Dd + d];   // transpose to [d][bk]
    ws[OFF_CB0 + g] = c0[g];                     // [32][1024] linear
  } else {
    int t = threadIdx.x;
    if (t < BKn) {
      ws[OFF_SC + t] = ((t & 3) == 0) ? 0.f : BIGf;
      wsi[IW + t] = words[t];
      wsi[IPREV + t] = t & 3;                    // identity gather for step 0
    }
    if (t < Bb) wsi[ISTOP + t] = 0;
    for (int i = t; i < 2 * Bb * Kk * Tt; i += 256) wsi[IBUFA + i] = 0;
  }
}

// gates partial GEMM. grid (32, 32): x = 128-col tile of f, y = d-chunk of 32.
__global__ __launch_bounds__(256) void gatesK(const float* __restrict__ Wx,
    const float* __restrict__ Wh, const float* __restrict__ E,
    const float* __restrict__ hTn, const int* __restrict__ wsi,
    float* __restrict__ Gp) {
  __shared__ float xs[GDC][BKn], hs[GDC][BKn];
  int tid = threadIdx.x;
  int d0 = blockIdx.y * GDC;
  {
    int bk = tid & 31, dq = tid >> 5;           // dq 0..7, 4 d each
    int w = wsi[IW + bk];
    int src = (bk & ~3) | wsi[IPREV + bk];
    const float* Erow = E + (size_t)w * Dd + d0;
#pragma unroll
    for (int k = 0; k < 4; k++) {
      int d = dq * 4 + k;
      xs[d][bk] = Erow[d];
      hs[d][bk] = hTn[(size_t)(d0 + d) * BKn + src];
    }
  }
  __syncthreads();
  int ct = tid & 31, bg = tid >> 5;             // 32 col-threads, 8 beam-groups
  int f0 = blockIdx.x * 128 + ct * 4;
  float acc[4][4];                               // [col][beam-in-group]
#pragma unroll
  for (int c = 0; c < 4; c++)
#pragma unroll
    for (int i = 0; i < 4; i++) acc[c][i] = 0.f;
#pragma unroll 4
  for (int d = 0; d < GDC; ++d) {
    float4 wx = *(const float4*)(Wx + (size_t)(d0 + d) * Ff + f0);
    float4 wh = *(const float4*)(Wh + (size_t)(d0 + d) * Ff + f0);
    float4 x4 = *(const float4*)&xs[d][bg * 4];
    float4 h4 = *(const float4*)&hs[d][bg * 4];
    float xv[4] = {x4.x, x4.y, x4.z, x4.w};
    float hv[4] = {h4.x, h4.y, h4.z, h4.w};
    float wxc[4] = {wx.x, wx.y, wx.z, wx.w};
    float whc[4] = {wh.x, wh.y, wh.z, wh.w};
#pragma unroll
    for (int c = 0; c < 4; c++)
#pragma unroll
      for (int i = 0; i < 4; i++)
        acc[c][i] = fmaf(xv[i], wxc[c], fmaf(hv[i], whc[c], acc[c][i]));
  }
#pragma unroll
  for (int i = 0; i < 4; i++) {
    int bk = bg * 4 + i;
    float4 o = {acc[0][i], acc[1][i], acc[2][i], acc[3][i]};
    *(float4*)(Gp + ((size_t)blockIdx.y * BKn + bk) * Ff + f0) = o;
  }
}

// reduce 32 gate partials + bias -> nonlinearity; gathers c by prev.
__global__ __launch_bounds__(256) void lstmK(const float* __restrict__ bvec,
    const float* __restrict__ Gp, const float* __restrict__ cPrev,
    const int* __restrict__ wsi, float* __restrict__ cNew,
    float* __restrict__ hTn) {
  __shared__ float part[4][128];
  int bk = blockIdx.x;
  int dcl = threadIdx.x & 127;
  int half = threadIdx.x >> 7;
  int dc = blockIdx.y * 128 + dcl;
  float s[4] = {0.f, 0.f, 0.f, 0.f};
#pragma unroll 4
  for (int dsl = 0; dsl < 16; dsl++) {
    int ds = half * 16 + dsl;
    const float* row = Gp + ((size_t)ds * BKn + bk) * Ff;
#pragma unroll
    for (int g = 0; g < 4; g++) s[g] += row[(size_t)g * Dd + dc];
  }
  if (half == 1) {
#pragma unroll
    for (int g = 0; g < 4; g++) part[g][dcl] = s[g];
  }
  __syncthreads();
  if (half == 0) {
    float gi = s[0] + part[0][dcl] + bvec[dc];
    float gf = s[1] + part[1][dcl] + bvec[Dd + dc];
    float gg = s[2] + part[2][dcl] + bvec[2 * Dd + dc];
    float go = s[3] + part[3][dcl] + bvec[3 * Dd + dc];
    int src = (bk & ~3) | wsi[IPREV + bk];
    float c = cPrev[(size_t)src * Dd + dc];
    float si = 1.f / (1.f + expf(-gi));
    float sf = 1.f / (1.f + expf(-gf));
    float so = 1.f / (1.f + expf(-go));
    float tg = tanhf(gg);
    float cn = sf * c + si * tg;
    float hn = so * tanhf(cn);
    cNew[(size_t)bk * Dd + dc] = cn;
    hTn[(size_t)dc * BKn + bk] = hn;
  }
}

// Async-staged full-depth logits + chunk stats. grid 1000 blocks x 256 thr.
// Block = 32 vocab cols x all 1024 d. Per 64-d chunk: DMA-stage Wo tile (8KB)
// + h chunk (8KB) into double-buffered LDS via global_load_lds (4 issues/wave),
// counted s_waitcnt vmcnt(4) + raw s_barrier (loads stay in flight across
// barriers -> deep MLP). FMA entirely from LDS. Then bias + stats -> cs.
__global__ __launch_bounds__(256) void logitsAK(const float* __restrict__ Wo,
    const float* __restrict__ bo, const float* __restrict__ hTn,
    float* __restrict__ cs) {
  __shared__ float wb[2][LCH][LTW];   // 16 KB
  __shared__ float hb[2][LCH][BKn];   // 16 KB
  __shared__ float sd[BKn][LTW];      // 4 KB
  int tid = threadIdx.x;
  int lane = tid & 63, wid = tid >> 6;
  int ct = tid & 7, bg = tid >> 3;    // 8 col-threads x 32 beams (1 beam each)
  size_t v0 = (size_t)blockIdx.x * LTW;
  float acc[4] = {0.f, 0.f, 0.f, 0.f};

  // bias load BEFORE the counted region (oldest outstanding, drains first)
  float4 b4 = *(const float4*)(bo + v0 + ct * 4);

#define STAGE(CH, B)                                                         \
  {                                                                          \
    int d0_ = (CH) * LCH;                                                    \
    _Pragma("unroll") for (int i_ = 0; i_ < 2; i_++) {                       \
      int r_ = i_ * 32 + wid * 8;                                            \
      cp16(Wo + (size_t)(d0_ + r_ + (lane >> 3)) * Vv + v0 + (lane & 7) * 4, \
           &wb[B][r_][0]);                                                   \
      cp16(hTn + (size_t)(d0_ + r_) * BKn + lane * 4, &hb[B][r_][0]);        \
    }                                                                        \
  }

  STAGE(0, 0)
  for (int ch = 0; ch < LNCH; ch++) {
    int b = ch & 1;
    if (ch + 1 < LNCH) {
      STAGE(ch + 1, b ^ 1)
      asm volatile("s_waitcnt vmcnt(4)" ::: "memory");  // chunk ch landed; ch+1 in flight
    } else {
      asm volatile("s_waitcnt vmcnt(0)" ::: "memory");
    }
    __builtin_amdgcn_s_barrier();
#pragma unroll 8
    for (int d = 0; d < LCH; d++) {
      float4 w4 = *(const float4*)&wb[b][d][ct * 4];
      float h = hb[b][d][bg];
      acc[0] = fmaf(w4.x, h, acc[0]);
      acc[1] = fmaf(w4.y, h, acc[1]);
      acc[2] = fmaf(w4.z, h, acc[2]);
      acc[3] = fmaf(w4.w, h, acc[3]);
    }
    __builtin_amdgcn_s_barrier();   // buf[b] free for overwrite next iter
  }
#undef STAGE

#pragma unroll
  for (int c = 0; c < 4; c++)
    sd[bg][ct * 4 + c] = acc[c] + ((const float*)&b4)[c];
  __syncthreads();

  // stats: 4 waves x (2 beams per 32-lane half x 4 iters) = 32 beams, 32 cols
  int l32 = lane & 31;
  int i0 = (int)v0 + l32;
  for (int bb_ = 0; bb_ < 4; ++bb_) {
    int bk = wid * 8 + bb_ * 2 + (lane >> 5);
    float v0f = sd[bk][l32];
    float m = v0f;
    for (int off = 16; off; off >>= 1) m = fmaxf(m, __shfl_xor(m, off));
    float se = expf(v0f - m);
    for (int off = 16; off; off >>= 1) se += __shfl_xor(se, off);
    float tv[4]; int ti[4];
#pragma unroll
    for (int r = 0; r < 4; r++) { tv[r] = -FLT_MAX; ti[r] = 0x7fffffff; }
    ins4(v0f, i0, tv, ti);
    float ov[4]; int oi[4];
    merge_top4<16>(tv, ti, ov, oi);
    if (l32 == 0) {
      float* p = cs + ((size_t)blockIdx.x * BKn + bk) * 12;
      p[0] = m; p[1] = se;
#pragma unroll
      for (int r = 0; r < 4; r++) { p[2 + r] = ov[r]; p[6 + r] = __int_as_float(oi[r]); }
    }
  }
}

// fused: per-beam online merge of 1000 chunk stats -> lse + top4; then exact
// selection, EOS logic, buf ping-pong. One block of 1024 threads.
// Loads batched in groups of 4 chunks via explicit float4 register arrays
// (compile-time indexed) so the allocator can't serialize them (R9 lesson:
// 28-VGPR allocation -> per-load vmcnt(0) -> 121us).
__global__ __launch_bounds__(1024) void redSelK(float* __restrict__ ws, int step) {
  __shared__ float bt_s[BKn][8];
  __shared__ int s_tok[BKn], s_prevb[BKn];
  int* wsi = (int*)(ws + OFF_INT);
  const float* cs = ws + OFF_CS;
  int tid = threadIdx.x;
  int wv = tid >> 6, lane = tid & 63;
  {
    int half = lane >> 5, l32 = lane & 31;
    int bk = wv * 2 + half;                 // 16 waves x 2 halves = 32 beams
    float tv[4]; int ti[4];
#pragma unroll
    for (int r = 0; r < 4; r++) { tv[r] = -FLT_MAX; ti[r] = 0x7fffffff; }
    float M = -FLT_MAX, ls = 0.f;
    for (int g = 0; g < 8; g++) {           // 8 groups x 4 chunks = 32 chunks/lane
      float4 pa[4], pb[4], pc[4];
      bool vv[4];
#pragma unroll
      for (int j = 0; j < 4; j++) {
        int c = l32 + 32 * (g * 4 + j);
        vv[j] = c < NVCH;
        const float* p = cs + ((size_t)c * BKn + bk) * 12;
        if (vv[j]) {
          pa[j] = *(const float4*)p;        // {m, se, ov0, ov1}
          pb[j] = *(const float4*)(p + 4);  // {ov2, ov3, oi0, oi1}
          pc[j] = *(const float4*)(p + 8);  // {oi2, oi3, -, -}
        }
      }
#pragma unroll
      for (int j = 0; j < 4; j++) {
        if (vv[j]) {
          float cm = pa[j].x, csum = pa[j].y;
          if (cm > M) { ls *= expf(M - cm); M = cm; }   // ls==0 when M==-inf
          ls += csum * expf(cm - M);
          ins4(pa[j].z, __float_as_int(pb[j].z), tv, ti);
          ins4(pa[j].w, __float_as_int(pb[j].w), tv, ti);
          ins4(pb[j].x, __float_as_int(pc[j].x), tv, ti);
          ins4(pb[j].y, __float_as_int(pc[j].y), tv, ti);
        }
      }
    }
    for (int off = 16; off; off >>= 1) {
      float Mo = __shfl_xor(M, off), lso = __shfl_xor(ls, off);
      float Mn = fmaxf(M, Mo);
      ls = ls * expf(M - Mn) + lso * expf(Mo - Mn);
      M = Mn;
    }
    float lse = M + logf(ls);
    float ov[4]; int oi[4];
    merge_top4<16>(tv, ti, ov, oi);
    if (l32 == 0) {
#pragma unroll
      for (int r = 0; r < 4; r++) {
        bt_s[bk][r] = lse - ov[r];
        bt_s[bk][4 + r] = __int_as_float(oi[r]);
      }
    }
  }
  __syncthreads();
  if (tid < Bb) {
    int b = tid;
    int st = wsi[ISTOP + b];
    float sc[4];
#pragma unroll
    for (int k = 0; k < 4; k++) sc[k] = ws[OFF_SC + b * 4 + k];
    float cval[16]; int ctok[16];
#pragma unroll
    for (int kb = 0; kb < 4; kb++)
#pragma unroll
      for (int r = 0; r < 4; r++) {
        cval[kb * 4 + r] = bt_s[b * 4 + kb][r] + sc[kb];
        ctok[kb * 4 + r] = __float_as_int(bt_s[b * 4 + kb][4 + r]);
      }
    float selS[4]; int selW[4], prevK[4];
    int usedMask = 0;
#pragma unroll
    for (int r = 0; r < 4; r++) {
      int best = -1; float bv = FLT_MAX;
#pragma unroll
      for (int t = 0; t < 16; t++) {
        if (!((usedMask >> t) & 1) && cval[t] < bv) { bv = cval[t]; best = t; }
      }
      usedMask |= 1 << best;
      int tok = 0;
#pragma unroll
      for (int t = 0; t < 16; t++) if (t == best) tok = ctok[t];   // no runtime index
      selS[r] = bv; selW[r] = tok; prevK[r] = best >> 2;
    }
    bool eos[4];
#pragma unroll
    for (int r = 0; r < 4; r++) eos[r] = (selW[r] == EOSt);
    bool first = eos[0] && !st;
#pragma unroll
    for (int r = 0; r < 4; r++) if (eos[r] && !first && !st) selS[r] = EOSSf;
#pragma unroll
    for (int k = 0; k < 4; k++) {
      int tok = st ? PADt : (first ? EOSt : selW[k]);
      int pb  = st ? k : prevK[k];
      s_tok[b * 4 + k] = tok;
      s_prevb[b * 4 + k] = pb;
      if (!st) { ws[OFF_SC + b * 4 + k] = selS[k]; wsi[IW + b * 4 + k] = selW[k]; }
      wsi[IPREV + b * 4 + k] = prevK[k];
    }
    wsi[ISTOP + b] = (st || first) ? 1 : 0;
  }
  __syncthreads();
  if (tid < 512) {
    const int* br = wsi + (((step & 1) == 0) ? IBUFA : IBUFB);
    int* bw = wsi + (((step & 1) == 0) ? IBUFB : IBUFA);
    int bkk = tid >> 4, t = tid & 15;
    int pb = s_prevb[bkk];
    int src = ((bkk & ~3) | pb) * Tt + t;
    int val = br[src];
    if (t == step) val = s_tok[bkk];
    bw[tid] = val;
  }
}

// Output read as float32 by harness: tokens as float values, scores as floats.
__global__ __launch_bounds__(256) void outK(const float* __restrict__ ws,
                                            float* __restrict__ out) {
  const int* wsi = (const int*)(ws + OFF_INT);
  int g = blockIdx.x * 256 + threadIdx.x;
  if (g < Bb * Kk * Tt) {
    out[g] = (float)wsi[IBUFA + g];               // final buf in A after 16 steps
  } else if (g < Bb * Kk * Tt + BKn) {
    out[g] = ws[OFF_SC + (g - Bb * Kk * Tt)];
  }
}

} // namespace

extern "C" void kernel_launch(void* const* d_in, const int* in_sizes, int n_in,
                              void* d_out, int out_size, void* d_ws, size_t ws_size,
                              hipStream_t stream) {
  (void)in_sizes; (void)n_in; (void)out_size; (void)ws_size;
  const int*   words = (const int*)d_in[0];
  const float* h0 = (const float*)d_in[1];
  const float* c0 = (const float*)d_in[2];
  const float* E  = (const float*)d_in[3];
  const float* Wx = (const float*)d_in[4];
  const float* Wh = (const float*)d_in[5];
  const float* bv = (const float*)d_in[6];
  const float* Wo = (const float*)d_in[7];
  const float* bo = (const float*)d_in[8];
  float* ws = (float*)d_ws;
  float* hTn = ws + OFF_HTN;
  float* cb0 = ws + OFF_CB0;
  float* cb1 = ws + OFF_CB1;
  float* Gp  = ws + OFF_GP;
  float* cs  = ws + OFF_CS;
  int*   wsi = (int*)(ws + OFF_INT);

  initK<<<129, 256, 0, stream>>>(words, h0, c0, ws);
  for (int j = 0; j < Tt; j++) {
    float* cPrev = (j & 1) ? cb1 : cb0;
    float* cNext = (j & 1) ? cb0 : cb1;
    gatesK<<<dim3(32, GDS), 256, 0, stream>>>(Wx, Wh, E, hTn, wsi, Gp);
    lstmK<<<dim3(32, 8), 256, 0, stream>>>(bv, Gp, cPrev, wsi, cNext, hTn);
    logitsAK<<<LNB, 256, 0, stream>>>(Wo, bo, hTn, cs);
    redSelK<<<1, 1024, 0, stream>>>(ws, j);
  }
  outK<<<3, 256, 0, stream>>>(ws, (float*)d_out);
}

// Round 11
// 1933.951 us; speedup vs baseline: 1.6664x; 1.2530x over previous
//
#include <hip/hip_runtime.h>
#include <math.h>
#include <float.h>

namespace {

constexpr int Bb = 8, Kk = 4, BKn = 32, Dd = 1024, Ff = 4096, Vv = 32000, Tt = 16;
constexpr int GDS = 32, GDC = 32;        // gates d-split / d-chunk  (32*32 = 1024)
constexpr int LTW = 64;                  // logits cols per block
constexpr int LNB = Vv / LTW;            // 500 blocks
constexpr int LCH = 32;                  // d per chunk
constexpr int LNCH = Dd / LCH;           // 32 chunks
constexpr int NVCH = LNB;                // 500 chunk-stat rows
constexpr int EOSt = 2, PADt = 0;
constexpr float BIGf = 1e9f, EOSSf = 1000.0f;

// ---- workspace layout (float indices) ----
constexpr size_t OFF_HTN = 0;                                   // hTn [1024][32]
constexpr size_t OFF_CB0 = OFF_HTN + (size_t)Dd * BKn;          // c ping [32][1024]
constexpr size_t OFF_CB1 = OFF_CB0 + (size_t)BKn * Dd;          // c pong
constexpr size_t OFF_GP  = OFF_CB1 + (size_t)BKn * Dd;          // gate partials [32][32][4096]
constexpr size_t OFF_CS  = OFF_GP  + (size_t)GDS * BKn * Ff;    // chunk stats [500][32][12]
constexpr size_t OFF_SC  = OFF_CS  + (size_t)NVCH * BKn * 12;   // scores [32]
constexpr size_t OFF_INT = OFF_SC  + BKn;                       // int region
constexpr int IW = 0, ISTOP = 32, IPREV = 40, IBUFA = 72, IBUFB = IBUFA + Bb * Kk * Tt;

__device__ __forceinline__ void cp16(const float* g, float* l) {
  __builtin_amdgcn_global_load_lds(
      (const __attribute__((address_space(1))) void*)g,
      (__attribute__((address_space(3))) void*)l, 16, 0, 0);
}

__device__ inline void ins4(float v, int id, float tv[4], int ti[4]) {
#pragma unroll
  for (int r = 0; r < 4; r++) {
    bool better = (v > tv[r]) || (v == tv[r] && id < ti[r]);
    if (better) { float fv = tv[r]; int fi = ti[r]; tv[r] = v; ti[r] = id; v = fv; id = fi; }
  }
}

// merge per-lane sorted top-4 into group-global top-4. STARTOFF=32 -> 64-lane wave,
// STARTOFF=16 -> independent 32-lane halves.
template <int STARTOFF>
__device__ inline void merge_top4(float tv[4], int ti[4], float ov[4], int oi[4]) {
#pragma unroll
  for (int r = 0; r < 4; r++) {
    float hv = tv[0]; int hi = ti[0];
    float m = hv;
    for (int off = STARTOFF; off; off >>= 1) m = fmaxf(m, __shfl_xor(m, off));
    int c = (hv == m) ? hi : 0x7fffffff;
    for (int off = STARTOFF; off; off >>= 1) c = min(c, __shfl_xor(c, off));
    if (hv == m && hi == c) {   // this lane's head won: pop
      tv[0] = tv[1]; ti[0] = ti[1];
      tv[1] = tv[2]; ti[1] = ti[2];
      tv[2] = tv[3]; ti[2] = ti[3];
      tv[3] = -FLT_MAX; ti[3] = 0x7fffffff;
    }
    ov[r] = m; oi[r] = c;
  }
}

__global__ __launch_bounds__(256) void initK(const int* __restrict__ words,
    const float* __restrict__ h0, const float* __restrict__ c0,
    float* __restrict__ ws) {
  int* wsi = (int*)(ws + OFF_INT);
  if (blockIdx.x < 128) {
    int g = blockIdx.x * 256 + threadIdx.x;   // 0..32767
    int d = g >> 5, bk = g & 31;
    ws[OFF_HTN + g] = h0[(size_t)bk * Dd + d];   // transpose to [d][bk]
    ws[OFF_CB0 + g] = c0[g];                     // [32][1024] linear
  } else {
    int t = threadIdx.x;
    if (t < BKn) {
      ws[OFF_SC + t] = ((t & 3) == 0) ? 0.f : BIGf;
      wsi[IW + t] = words[t];
      wsi[IPREV + t] = t & 3;                    // identity gather for step 0
    }
    if (t < Bb) wsi[ISTOP + t] = 0;
    for (int i = t; i < 2 * Bb * Kk * Tt; i += 256) wsi[IBUFA + i] = 0;
  }
}

// gates partial GEMM. grid (32, 32): x = 128-col tile of f, y = d-chunk of 32.
__global__ __launch_bounds__(256) void gatesK(const float* __restrict__ Wx,
    const float* __restrict__ Wh, const float* __restrict__ E,
    const float* __restrict__ hTn, const int* __restrict__ wsi,
    float* __restrict__ Gp) {
  __shared__ float xs[GDC][BKn], hs[GDC][BKn];
  int tid = threadIdx.x;
  int d0 = blockIdx.y * GDC;
  {
    int bk = tid & 31, dq = tid >> 5;           // dq 0..7, 4 d each
    int w = wsi[IW + bk];
    int src = (bk & ~3) | wsi[IPREV + bk];
    const float* Erow = E + (size_t)w * Dd + d0;
#pragma unroll
    for (int k = 0; k < 4; k++) {
      int d = dq * 4 + k;
      xs[d][bk] = Erow[d];
      hs[d][bk] = hTn[(size_t)(d0 + d) * BKn + src];
    }
  }
  __syncthreads();
  int ct = tid & 31, bg = tid >> 5;             // 32 col-threads, 8 beam-groups
  int f0 = blockIdx.x * 128 + ct * 4;
  float acc[4][4];                               // [col][beam-in-group]
#pragma unroll
  for (int c = 0; c < 4; c++)
#pragma unroll
    for (int i = 0; i < 4; i++) acc[c][i] = 0.f;
#pragma unroll 4
  for (int d = 0; d < GDC; ++d) {
    float4 wx = *(const float4*)(Wx + (size_t)(d0 + d) * Ff + f0);
    float4 wh = *(const float4*)(Wh + (size_t)(d0 + d) * Ff + f0);
    float4 x4 = *(const float4*)&xs[d][bg * 4];
    float4 h4 = *(const float4*)&hs[d][bg * 4];
    float xv[4] = {x4.x, x4.y, x4.z, x4.w};
    float hv[4] = {h4.x, h4.y, h4.z, h4.w};
    float wxc[4] = {wx.x, wx.y, wx.z, wx.w};
    float whc[4] = {wh.x, wh.y, wh.z, wh.w};
#pragma unroll
    for (int c = 0; c < 4; c++)
#pragma unroll
      for (int i = 0; i < 4; i++)
        acc[c][i] = fmaf(xv[i], wxc[c], fmaf(hv[i], whc[c], acc[c][i]));
  }
#pragma unroll
  for (int i = 0; i < 4; i++) {
    int bk = bg * 4 + i;
    float4 o = {acc[0][i], acc[1][i], acc[2][i], acc[3][i]};
    *(float4*)(Gp + ((size_t)blockIdx.y * BKn + bk) * Ff + f0) = o;
  }
}

// reduce 32 gate partials + bias -> nonlinearity; gathers c by prev.
__global__ __launch_bounds__(256) void lstmK(const float* __restrict__ bvec,
    const float* __restrict__ Gp, const float* __restrict__ cPrev,
    const int* __restrict__ wsi, float* __restrict__ cNew,
    float* __restrict__ hTn) {
  __shared__ float part[4][128];
  int bk = blockIdx.x;
  int dcl = threadIdx.x & 127;
  int half = threadIdx.x >> 7;
  int dc = blockIdx.y * 128 + dcl;
  float s[4] = {0.f, 0.f, 0.f, 0.f};
#pragma unroll 4
  for (int dsl = 0; dsl < 16; dsl++) {
    int ds = half * 16 + dsl;
    const float* row = Gp + ((size_t)ds * BKn + bk) * Ff;
#pragma unroll
    for (int g = 0; g < 4; g++) s[g] += row[(size_t)g * Dd + dc];
  }
  if (half == 1) {
#pragma unroll
    for (int g = 0; g < 4; g++) part[g][dcl] = s[g];
  }
  __syncthreads();
  if (half == 0) {
    float gi = s[0] + part[0][dcl] + bvec[dc];
    float gf = s[1] + part[1][dcl] + bvec[Dd + dc];
    float gg = s[2] + part[2][dcl] + bvec[2 * Dd + dc];
    float go = s[3] + part[3][dcl] + bvec[3 * Dd + dc];
    int src = (bk & ~3) | wsi[IPREV + bk];
    float c = cPrev[(size_t)src * Dd + dc];
    float si = 1.f / (1.f + expf(-gi));
    float sf = 1.f / (1.f + expf(-gf));
    float so = 1.f / (1.f + expf(-go));
    float tg = tanhf(gg);
    float cn = sf * c + si * tg;
    float hn = so * tanhf(cn);
    cNew[(size_t)bk * Dd + dc] = cn;
    hTn[(size_t)dc * BKn + bk] = hn;
  }
}

// Async-staged full-depth logits + chunk stats, register-blocked 4col x 2beam.
// grid 500 blocks x 256 thr (4 waves). Block = 64 vocab cols x all 1024 d.
// Per 32-d chunk: DMA-stage Wo tile (8KB) + h chunk (4KB) into double-buffered
// LDS (3 global_load_lds per wave), counted s_waitcnt vmcnt(3) + raw s_barrier.
// Per d each thread: 1 ds_read_b128 (4 cols) + 1 ds_read_b64 (2 beams) -> 8 FMA.
__global__ __launch_bounds__(256) void logitsAK(const float* __restrict__ Wo,
    const float* __restrict__ bo, const float* __restrict__ hTn,
    float* __restrict__ cs) {
  __shared__ float wb[2][LCH][LTW];   // 16 KB
  __shared__ float hb[2][LCH][BKn];   // 8 KB
  __shared__ float sd[BKn][LTW];      // 8 KB
  int tid = threadIdx.x;
  int lane = tid & 63, wid = tid >> 6;
  int ct = tid & 15, bg = tid >> 4;   // 16 col-groups x 16 beam-pairs
  size_t v0 = (size_t)blockIdx.x * LTW;
  float acc[4][2];
#pragma unroll
  for (int c = 0; c < 4; c++) { acc[c][0] = 0.f; acc[c][1] = 0.f; }

  // bias load BEFORE the counted region (oldest outstanding, drains first)
  float4 b4 = *(const float4*)(bo + v0 + ct * 4);

#define STAGE(CH, B)                                                          \
  {                                                                           \
    int d0_ = (CH) * LCH;                                                     \
    _Pragma("unroll") for (int i_ = 0; i_ < 2; i_++) {                        \
      int r_ = i_ * 16 + wid * 4;                                             \
      cp16(Wo + (size_t)(d0_ + r_ + (lane >> 4)) * Vv + v0 + (lane & 15) * 4, \
           &wb[B][r_][0]);                                                    \
    }                                                                         \
    cp16(hTn + (size_t)(d0_ + wid * 8) * BKn + lane * 4, &hb[B][wid * 8][0]); \
  }

  STAGE(0, 0)
  for (int ch = 0; ch < LNCH; ch++) {
    int b = ch & 1;
    if (ch + 1 < LNCH) {
      STAGE(ch + 1, b ^ 1)
      asm volatile("s_waitcnt vmcnt(3)" ::: "memory");  // chunk ch landed; ch+1 in flight
    } else {
      asm volatile("s_waitcnt vmcnt(0)" ::: "memory");
    }
    __builtin_amdgcn_s_barrier();
#pragma unroll 8
    for (int d = 0; d < LCH; d++) {
      float4 w4 = *(const float4*)&wb[b][d][ct * 4];
      float2 h2 = *(const float2*)&hb[b][d][bg * 2];
      acc[0][0] = fmaf(w4.x, h2.x, acc[0][0]);
      acc[1][0] = fmaf(w4.y, h2.x, acc[1][0]);
      acc[2][0] = fmaf(w4.z, h2.x, acc[2][0]);
      acc[3][0] = fmaf(w4.w, h2.x, acc[3][0]);
      acc[0][1] = fmaf(w4.x, h2.y, acc[0][1]);
      acc[1][1] = fmaf(w4.y, h2.y, acc[1][1]);
      acc[2][1] = fmaf(w4.z, h2.y, acc[2][1]);
      acc[3][1] = fmaf(w4.w, h2.y, acc[3][1]);
    }
    __builtin_amdgcn_s_barrier();   // buf[b] free for overwrite next iter
  }
#undef STAGE

#pragma unroll
  for (int c = 0; c < 4; c++) {
    sd[bg * 2 + 0][ct * 4 + c] = acc[c][0] + ((const float*)&b4)[c];
    sd[bg * 2 + 1][ct * 4 + c] = acc[c][1] + ((const float*)&b4)[c];
  }
  __syncthreads();

  // stats: 4 waves x 8 beams = 32 beams, full 64-lane wave over 64 cols
  int i0 = (int)v0 + lane;
  for (int bb_ = 0; bb_ < 8; ++bb_) {
    int bk = wid * 8 + bb_;
    float v0f = sd[bk][lane];
    float m = v0f;
    for (int off = 32; off; off >>= 1) m = fmaxf(m, __shfl_xor(m, off));
    float se = expf(v0f - m);
    for (int off = 32; off; off >>= 1) se += __shfl_xor(se, off);
    float tv[4]; int ti[4];
#pragma unroll
    for (int r = 0; r < 4; r++) { tv[r] = -FLT_MAX; ti[r] = 0x7fffffff; }
    ins4(v0f, i0, tv, ti);
    float ov[4]; int oi[4];
    merge_top4<32>(tv, ti, ov, oi);
    if (lane == 0) {
      float* p = cs + ((size_t)blockIdx.x * BKn + bk) * 12;
      p[0] = m; p[1] = se;
#pragma unroll
      for (int r = 0; r < 4; r++) { p[2 + r] = ov[r]; p[6 + r] = __int_as_float(oi[r]); }
    }
  }
}

// fused: per-beam online merge of 500 chunk stats -> lse + top4; then exact
// selection, EOS logic, buf ping-pong. One block of 1024 threads.
// Loads batched in groups of 4 chunks via explicit float4 register arrays.
__global__ __launch_bounds__(1024) void redSelK(float* __restrict__ ws, int step) {
  __shared__ float bt_s[BKn][8];
  __shared__ int s_tok[BKn], s_prevb[BKn];
  int* wsi = (int*)(ws + OFF_INT);
  const float* cs = ws + OFF_CS;
  int tid = threadIdx.x;
  int wv = tid >> 6, lane = tid & 63;
  {
    int half = lane >> 5, l32 = lane & 31;
    int bk = wv * 2 + half;                 // 16 waves x 2 halves = 32 beams
    float tv[4]; int ti[4];
#pragma unroll
    for (int r = 0; r < 4; r++) { tv[r] = -FLT_MAX; ti[r] = 0x7fffffff; }
    float M = -FLT_MAX, ls = 0.f;
    for (int g = 0; g < 4; g++) {           // 4 groups x 4 chunks = 16 chunks/lane
      float4 pa[4], pb[4], pc[4];
      bool vv[4];
#pragma unroll
      for (int j = 0; j < 4; j++) {
        int c = l32 + 32 * (g * 4 + j);
        vv[j] = c < NVCH;
        const float* p = cs + ((size_t)c * BKn + bk) * 12;
        if (vv[j]) {
          pa[j] = *(const float4*)p;        // {m, se, ov0, ov1}
          pb[j] = *(const float4*)(p + 4);  // {ov2, ov3, oi0, oi1}
          pc[j] = *(const float4*)(p + 8);  // {oi2, oi3, -, -}
        }
      }
#pragma unroll
      for (int j = 0; j < 4; j++) {
        if (vv[j]) {
          float cm = pa[j].x, csum = pa[j].y;
          if (cm > M) { ls *= expf(M - cm); M = cm; }   // ls==0 when M==-inf
          ls += csum * expf(cm - M);
          ins4(pa[j].z, __float_as_int(pb[j].z), tv, ti);
          ins4(pa[j].w, __float_as_int(pb[j].w), tv, ti);
          ins4(pb[j].x, __float_as_int(pc[j].x), tv, ti);
          ins4(pb[j].y, __float_as_int(pc[j].y), tv, ti);
        }
      }
    }
    for (int off = 16; off; off >>= 1) {
      float Mo = __shfl_xor(M, off), lso = __shfl_xor(ls, off);
      float Mn = fmaxf(M, Mo);
      ls = ls * expf(M - Mn) + lso * expf(Mo - Mn);
      M = Mn;
    }
    float lse = M + logf(ls);
    float ov[4]; int oi[4];
    merge_top4<16>(tv, ti, ov, oi);
    if (l32 == 0) {
#pragma unroll
      for (int r = 0; r < 4; r++) {
        bt_s[bk][r] = lse - ov[r];
        bt_s[bk][4 + r] = __int_as_float(oi[r]);
      }
    }
  }
  __syncthreads();
  if (tid < Bb) {
    int b = tid;
    int st = wsi[ISTOP + b];
    float sc[4];
#pragma unroll
    for (int k = 0; k < 4; k++) sc[k] = ws[OFF_SC + b * 4 + k];
    float cval[16]; int ctok[16];
#pragma unroll
    for (int kb = 0; kb < 4; kb++)
#pragma unroll
      for (int r = 0; r < 4; r++) {
        cval[kb * 4 + r] = bt_s[b * 4 + kb][r] + sc[kb];
        ctok[kb * 4 + r] = __float_as_int(bt_s[b * 4 + kb][4 + r]);
      }
    float selS[4]; int selW[4], prevK[4];
    int usedMask = 0;
#pragma unroll
    for (int r = 0; r < 4; r++) {
      int best = -1; float bv = FLT_MAX;
#pragma unroll
      for (int t = 0; t < 16; t++) {
        if (!((usedMask >> t) & 1) && cval[t] < bv) { bv = cval[t]; best = t; }
      }
      usedMask |= 1 << best;
      int tok = 0;
#pragma unroll
      for (int t = 0; t < 16; t++) if (t == best) tok = ctok[t];   // no runtime index
      selS[r] = bv; selW[r] = tok; prevK[r] = best >> 2;
    }
    bool eos[4];
#pragma unroll
    for (int r = 0; r < 4; r++) eos[r] = (selW[r] == EOSt);
    bool first = eos[0] && !st;
#pragma unroll
    for (int r = 0; r < 4; r++) if (eos[r] && !first && !st) selS[r] = EOSSf;
#pragma unroll
    for (int k = 0; k < 4; k++) {
      int tok = st ? PADt : (first ? EOSt : selW[k]);
      int pb  = st ? k : prevK[k];
      s_tok[b * 4 + k] = tok;
      s_prevb[b * 4 + k] = pb;
      if (!st) { ws[OFF_SC + b * 4 + k] = selS[k]; wsi[IW + b * 4 + k] = selW[k]; }
      wsi[IPREV + b * 4 + k] = prevK[k];
    }
    wsi[ISTOP + b] = (st || first) ? 1 : 0;
  }
  __syncthreads();
  if (tid < 512) {
    const int* br = wsi + (((step & 1) == 0) ? IBUFA : IBUFB);
    int* bw = wsi + (((step & 1) == 0) ? IBUFB : IBUFA);
    int bkk = tid >> 4, t = tid & 15;
    int pb = s_prevb[bkk];
    int src = ((bkk & ~3) | pb) * Tt + t;
    int val = br[src];
    if (t == step) val = s_tok[bkk];
    bw[tid] = val;
  }
}

// Output read as float32 by harness: tokens as float values, scores as floats.
__global__ __launch_bounds__(256) void outK(const float* __restrict__ ws,
                                            float* __restrict__ out) {
  const int* wsi = (const int*)(ws + OFF_INT);
  int g = blockIdx.x * 256 + threadIdx.x;
  if (g < Bb * Kk * Tt) {
    out[g] = (float)wsi[IBUFA + g];               // final buf in A after 16 steps
  } else if (g < Bb * Kk * Tt + BKn) {
    out[g] = ws[OFF_SC + (g - Bb * Kk * Tt)];
  }
}

} // namespace

extern "C" void kernel_launch(void* const* d_in, const int* in_sizes, int n_in,
                              void* d_out, int out_size, void* d_ws, size_t ws_size,
                              hipStream_t stream) {
  (void)in_sizes; (void)n_in; (void)out_size; (void)ws_size;
  const int*   words = (const int*)d_in[0];
  const float* h0 = (const float*)d_in[1];
  const float* c0 = (const float*)d_in[2];
  const float* E  = (const float*)d_in[3];
  const float* Wx = (const float*)d_in[4];
  const float* Wh = (const float*)d_in[5];
  const float* bv = (const float*)d_in[6];
  const float* Wo = (const float*)d_in[7];
  const float* bo = (const float*)d_in[8];
  float* ws = (float*)d_ws;
  float* hTn = ws + OFF_HTN;
  float* cb0 = ws + OFF_CB0;
  float* cb1 = ws + OFF_CB1;
  float* Gp  = ws + OFF_GP;
  float* cs  = ws + OFF_CS;
  int*   wsi = (int*)(ws + OFF_INT);

  initK<<<129, 256, 0, stream>>>(words, h0, c0, ws);
  for (int j = 0; j < Tt; j++) {
    float* cPrev = (j & 1) ? cb1 : cb0;
    float* cNext = (j & 1) ? cb0 : cb1;
    gatesK<<<dim3(32, GDS), 256, 0, stream>>>(Wx, Wh, E, hTn, wsi, Gp);
    lstmK<<<dim3(32, 8), 256, 0, stream>>>(bv, Gp, cPrev, wsi, cNext, hTn);
    logitsAK<<<LNB, 256, 0, stream>>>(Wo, bo, hTn, cs);
    redSelK<<<1, 1024, 0, stream>>>(ws, j);
  }
  outK<<<3, 256, 0, stream>>>(ws, (float*)d_out);
}

// Round 12
// 1779.670 us; speedup vs baseline: 1.8108x; 1.0867x over previous
//
#include <hip/hip_runtime.h>
#include <math.h>
#include <float.h>

namespace {

constexpr int Bb = 8, Kk = 4, BKn = 32, Dd = 1024, Ff = 4096, Vv = 32000, Tt = 16;
constexpr int GDS = 32, GDC = 32;        // gates d-split / d-chunk  (32*32 = 1024)
constexpr int LTW = 64;                  // logits cols per block
constexpr int LNB = Vv / LTW;            // 500 blocks
constexpr int LCH = 32;                  // d per chunk (per half)
constexpr int LNCHH = 16;                // chunks per half (16*32 = 512 d)
constexpr int NVCH = LNB;                // 500 chunk-stat rows
constexpr int EOSt = 2, PADt = 0;
constexpr float BIGf = 1e9f, EOSSf = 1000.0f;

// ---- workspace layout (float indices) ----
constexpr size_t OFF_HTN = 0;                                   // hTn [1024][32]
constexpr size_t OFF_CB0 = OFF_HTN + (size_t)Dd * BKn;          // c ping [32][1024]
constexpr size_t OFF_CB1 = OFF_CB0 + (size_t)BKn * Dd;          // c pong
constexpr size_t OFF_GP  = OFF_CB1 + (size_t)BKn * Dd;          // gate partials [32][32][4096]
constexpr size_t OFF_CS  = OFF_GP  + (size_t)GDS * BKn * Ff;    // chunk stats [500][32][12]
constexpr size_t OFF_SC  = OFF_CS  + (size_t)NVCH * BKn * 12;   // scores [32]
constexpr size_t OFF_INT = OFF_SC  + BKn;                       // int region
constexpr int IW = 0, ISTOP = 32, IPREV = 40, IBUFA = 72, IBUFB = IBUFA + Bb * Kk * Tt;

__device__ __forceinline__ void cp16(const float* g, float* l) {
  __builtin_amdgcn_global_load_lds(
      (const __attribute__((address_space(1))) void*)g,
      (__attribute__((address_space(3))) void*)l, 16, 0, 0);
}

__device__ inline void ins4(float v, int id, float tv[4], int ti[4]) {
#pragma unroll
  for (int r = 0; r < 4; r++) {
    bool better = (v > tv[r]) || (v == tv[r] && id < ti[r]);
    if (better) { float fv = tv[r]; int fi = ti[r]; tv[r] = v; ti[r] = id; v = fv; id = fi; }
  }
}

// merge per-lane sorted top-4 into group-global top-4. STARTOFF=32 -> 64-lane wave,
// STARTOFF=16 -> independent 32-lane halves.
template <int STARTOFF>
__device__ inline void merge_top4(float tv[4], int ti[4], float ov[4], int oi[4]) {
#pragma unroll
  for (int r = 0; r < 4; r++) {
    float hv = tv[0]; int hi = ti[0];
    float m = hv;
    for (int off = STARTOFF; off; off >>= 1) m = fmaxf(m, __shfl_xor(m, off));
    int c = (hv == m) ? hi : 0x7fffffff;
    for (int off = STARTOFF; off; off >>= 1) c = min(c, __shfl_xor(c, off));
    if (hv == m && hi == c) {   // this lane's head won: pop
      tv[0] = tv[1]; ti[0] = ti[1];
      tv[1] = tv[2]; ti[1] = ti[2];
      tv[2] = tv[3]; ti[2] = ti[3];
      tv[3] = -FLT_MAX; ti[3] = 0x7fffffff;
    }
    ov[r] = m; oi[r] = c;
  }
}

__global__ __launch_bounds__(256) void initK(const int* __restrict__ words,
    const float* __restrict__ h0, const float* __restrict__ c0,
    float* __restrict__ ws) {
  int* wsi = (int*)(ws + OFF_INT);
  if (blockIdx.x < 128) {
    int g = blockIdx.x * 256 + threadIdx.x;   // 0..32767
    int d = g >> 5, bk = g & 31;
    ws[OFF_HTN + g] = h0[(size_t)bk * Dd + d];   // transpose to [d][bk]
    ws[OFF_CB0 + g] = c0[g];                     // [32][1024] linear
  } else {
    int t = threadIdx.x;
    if (t < BKn) {
      ws[OFF_SC + t] = ((t & 3) == 0) ? 0.f : BIGf;
      wsi[IW + t] = words[t];
      wsi[IPREV + t] = t & 3;                    // identity gather for step 0
    }
    if (t < Bb) wsi[ISTOP + t] = 0;
    for (int i = t; i < 2 * Bb * Kk * Tt; i += 256) wsi[IBUFA + i] = 0;
  }
}

// gates partial GEMM. grid (32, 32): x = 128-col tile of f, y = d-chunk of 32.
__global__ __launch_bounds__(256) void gatesK(const float* __restrict__ Wx,
    const float* __restrict__ Wh, const float* __restrict__ E,
    const float* __restrict__ hTn, const int* __restrict__ wsi,
    float* __restrict__ Gp) {
  __shared__ float xs[GDC][BKn], hs[GDC][BKn];
  int tid = threadIdx.x;
  int d0 = blockIdx.y * GDC;
  {
    int bk = tid & 31, dq = tid >> 5;           // dq 0..7, 4 d each
    int w = wsi[IW + bk];
    int src = (bk & ~3) | wsi[IPREV + bk];
    const float* Erow = E + (size_t)w * Dd + d0;
#pragma unroll
    for (int k = 0; k < 4; k++) {
      int d = dq * 4 + k;
      xs[d][bk] = Erow[d];
      hs[d][bk] = hTn[(size_t)(d0 + d) * BKn + src];
    }
  }
  __syncthreads();
  int ct = tid & 31, bg = tid >> 5;             // 32 col-threads, 8 beam-groups
  int f0 = blockIdx.x * 128 + ct * 4;
  float acc[4][4];                               // [col][beam-in-group]
#pragma unroll
  for (int c = 0; c < 4; c++)
#pragma unroll
    for (int i = 0; i < 4; i++) acc[c][i] = 0.f;
#pragma unroll 4
  for (int d = 0; d < GDC; ++d) {
    float4 wx = *(const float4*)(Wx + (size_t)(d0 + d) * Ff + f0);
    float4 wh = *(const float4*)(Wh + (size_t)(d0 + d) * Ff + f0);
    float4 x4 = *(const float4*)&xs[d][bg * 4];
    float4 h4 = *(const float4*)&hs[d][bg * 4];
    float xv[4] = {x4.x, x4.y, x4.z, x4.w};
    float hv[4] = {h4.x, h4.y, h4.z, h4.w};
    float wxc[4] = {wx.x, wx.y, wx.z, wx.w};
    float whc[4] = {wh.x, wh.y, wh.z, wh.w};
#pragma unroll
    for (int c = 0; c < 4; c++)
#pragma unroll
      for (int i = 0; i < 4; i++)
        acc[c][i] = fmaf(xv[i], wxc[c], fmaf(hv[i], whc[c], acc[c][i]));
  }
#pragma unroll
  for (int i = 0; i < 4; i++) {
    int bk = bg * 4 + i;
    float4 o = {acc[0][i], acc[1][i], acc[2][i], acc[3][i]};
    *(float4*)(Gp + ((size_t)blockIdx.y * BKn + bk) * Ff + f0) = o;
  }
}

// reduce 32 gate partials + bias -> nonlinearity; gathers c by prev.
__global__ __launch_bounds__(256) void lstmK(const float* __restrict__ bvec,
    const float* __restrict__ Gp, const float* __restrict__ cPrev,
    const int* __restrict__ wsi, float* __restrict__ cNew,
    float* __restrict__ hTn) {
  __shared__ float part[4][128];
  int bk = blockIdx.x;
  int dcl = threadIdx.x & 127;
  int half = threadIdx.x >> 7;
  int dc = blockIdx.y * 128 + dcl;
  float s[4] = {0.f, 0.f, 0.f, 0.f};
#pragma unroll 4
  for (int dsl = 0; dsl < 16; dsl++) {
    int ds = half * 16 + dsl;
    const float* row = Gp + ((size_t)ds * BKn + bk) * Ff;
#pragma unroll
    for (int g = 0; g < 4; g++) s[g] += row[(size_t)g * Dd + dc];
  }
  if (half == 1) {
#pragma unroll
    for (int g = 0; g < 4; g++) part[g][dcl] = s[g];
  }
  __syncthreads();
  if (half == 0) {
    float gi = s[0] + part[0][dcl] + bvec[dc];
    float gf = s[1] + part[1][dcl] + bvec[Dd + dc];
    float gg = s[2] + part[2][dcl] + bvec[2 * Dd + dc];
    float go = s[3] + part[3][dcl] + bvec[3 * Dd + dc];
    int src = (bk & ~3) | wsi[IPREV + bk];
    float c = cPrev[(size_t)src * Dd + dc];
    float si = 1.f / (1.f + expf(-gi));
    float sf = 1.f / (1.f + expf(-gf));
    float so = 1.f / (1.f + expf(-go));
    float tg = tanhf(gg);
    float cn = sf * c + si * tg;
    float hn = so * tanhf(cn);
    cNew[(size_t)bk * Dd + dc] = cn;
    hTn[(size_t)dc * BKn + bk] = hn;
  }
}

// Async-staged full-depth logits + chunk stats, 4col x 4beam register tile,
// triple-buffered DMA staging with prefetch distance 2.
// grid 500 blocks x 256 thr. Block = 64 vocab cols; threads split into two
// d-halves (512 d each, 16 chunks of 32 d); each half = 16 col-groups x
// 8 beam-groups. Per chunk each wave issues 6 global_load_lds (4 Wo + 2 h);
// steady-state wait is vmcnt(12) (2 chunks in flight), never 0 until drain.
// Per d each thread: 2 ds_read_b128 -> 16 FMA (2 B/FMA LDS traffic, half of
// R11's 3 B/FMA). Halves combine in sd at the end; then per-block stats.
__global__ __launch_bounds__(256) void logitsAK(const float* __restrict__ Wo,
    const float* __restrict__ bo, const float* __restrict__ hTn,
    float* __restrict__ cs) {
  __shared__ float wb[2][3][LCH][LTW];   // 48 KB
  __shared__ float hb[2][3][LCH][BKn];   // 24 KB
  __shared__ float sd[BKn][LTW];         // 8 KB   (total 80 KB -> 2 blocks/CU)
  int tid = threadIdx.x;
  int half = tid >> 7;                // d-half 0/1
  int htid = tid & 127;
  int hw = htid >> 6;                 // wave within half (0,1)
  int lane = tid & 63;
  int cg = htid & 15;                 // col group (4 cols)
  int bg = htid >> 4;                 // beam group (4 beams), 0..7
  size_t v0 = (size_t)blockIdx.x * LTW;
  int dh0 = half * 512;
  float acc[4][4];                    // [col][beam]
#pragma unroll
  for (int c = 0; c < 4; c++)
#pragma unroll
    for (int i = 0; i < 4; i++) acc[c][i] = 0.f;

  // bias: 1 VMEM per wave, issued FIRST (drains with chunk 0's wait)
  float4 b4 = *(const float4*)(bo + v0 + cg * 4);

  // per-wave stage of chunk CH into buf B: 4 Wo cp16 (16 d-rows) + 2 h cp16
#define STAGE(CH, B)                                                           \
  {                                                                            \
    int d0_ = dh0 + (CH) * LCH;                                                \
    _Pragma("unroll") for (int i_ = 0; i_ < 4; i_++) {                         \
      int db_ = hw * 16 + i_ * 4;                                              \
      cp16(Wo + (size_t)(d0_ + db_ + (lane >> 4)) * Vv + v0 + (lane & 15) * 4, \
           &wb[half][B][db_][0]);                                              \
    }                                                                          \
    _Pragma("unroll") for (int j_ = 0; j_ < 2; j_++) {                         \
      int db_ = hw * 16 + j_ * 8;                                              \
      cp16(hTn + (size_t)(d0_ + db_ + (lane >> 3)) * BKn + (lane & 7) * 4,     \
           &hb[half][B][db_][0]);                                              \
    }                                                                          \
  }

  STAGE(0, 0)
  STAGE(1, 1)
  for (int k = 0; k < LNCHH; k++) {
    int b = k % 3;
    if (k + 2 < LNCHH) {
      STAGE(k + 2, (k + 2) % 3)
      asm volatile("s_waitcnt vmcnt(12)" ::: "memory");  // chunk k landed
    } else if (k + 1 < LNCHH) {
      asm volatile("s_waitcnt vmcnt(6)" ::: "memory");
    } else {
      asm volatile("s_waitcnt vmcnt(0)" ::: "memory");
    }
    __builtin_amdgcn_s_barrier();
#pragma unroll 8
    for (int d = 0; d < LCH; d++) {
      float4 w4 = *(const float4*)&wb[half][b][d][cg * 4];
      float4 h4 = *(const float4*)&hb[half][b][d][bg * 4];
      acc[0][0] = fmaf(w4.x, h4.x, acc[0][0]);
      acc[1][0] = fmaf(w4.y, h4.x, acc[1][0]);
      acc[2][0] = fmaf(w4.z, h4.x, acc[2][0]);
      acc[3][0] = fmaf(w4.w, h4.x, acc[3][0]);
      acc[0][1] = fmaf(w4.x, h4.y, acc[0][1]);
      acc[1][1] = fmaf(w4.y, h4.y, acc[1][1]);
      acc[2][1] = fmaf(w4.z, h4.y, acc[2][1]);
      acc[3][1] = fmaf(w4.w, h4.y, acc[3][1]);
      acc[0][2] = fmaf(w4.x, h4.z, acc[0][2]);
      acc[1][2] = fmaf(w4.y, h4.z, acc[1][2]);
      acc[2][2] = fmaf(w4.z, h4.z, acc[2][2]);
      acc[3][2] = fmaf(w4.w, h4.z, acc[3][2]);
      acc[0][3] = fmaf(w4.x, h4.w, acc[0][3]);
      acc[1][3] = fmaf(w4.y, h4.w, acc[1][3]);
      acc[2][3] = fmaf(w4.z, h4.w, acc[2][3]);
      acc[3][3] = fmaf(w4.w, h4.w, acc[3][3]);
    }
    __builtin_amdgcn_s_barrier();   // buf b free for overwrite at iter k+1
  }
#undef STAGE

  // combine halves in sd: half 0 writes (+bias), half 1 accumulates
  if (half == 0) {
#pragma unroll
    for (int c = 0; c < 4; c++)
#pragma unroll
      for (int i = 0; i < 4; i++)
        sd[bg * 4 + i][cg * 4 + c] = acc[c][i] + ((const float*)&b4)[c];
  }
  __syncthreads();
  if (half == 1) {
#pragma unroll
    for (int c = 0; c < 4; c++)
#pragma unroll
      for (int i = 0; i < 4; i++)
        sd[bg * 4 + i][cg * 4 + c] += acc[c][i];
  }
  __syncthreads();

  // stats: 4 waves x 8 beams = 32 beams, full 64-lane wave over 64 cols
  int wid = tid >> 6;
  int i0 = (int)v0 + lane;
  for (int bb_ = 0; bb_ < 8; ++bb_) {
    int bk = wid * 8 + bb_;
    float v0f = sd[bk][lane];
    float m = v0f;
    for (int off = 32; off; off >>= 1) m = fmaxf(m, __shfl_xor(m, off));
    float se = expf(v0f - m);
    for (int off = 32; off; off >>= 1) se += __shfl_xor(se, off);
    float tv[4]; int ti[4];
#pragma unroll
    for (int r = 0; r < 4; r++) { tv[r] = -FLT_MAX; ti[r] = 0x7fffffff; }
    ins4(v0f, i0, tv, ti);
    float ov[4]; int oi[4];
    merge_top4<32>(tv, ti, ov, oi);
    if (lane == 0) {
      float* p = cs + ((size_t)blockIdx.x * BKn + bk) * 12;
      p[0] = m; p[1] = se;
#pragma unroll
      for (int r = 0; r < 4; r++) { p[2 + r] = ov[r]; p[6 + r] = __int_as_float(oi[r]); }
    }
  }
}

// fused: per-beam online merge of 500 chunk stats -> lse + top4; then exact
// selection, EOS logic, buf ping-pong. One block of 1024 threads.
// Loads batched in groups of 4 chunks via explicit float4 register arrays.
__global__ __launch_bounds__(1024) void redSelK(float* __restrict__ ws, int step) {
  __shared__ float bt_s[BKn][8];
  __shared__ int s_tok[BKn], s_prevb[BKn];
  int* wsi = (int*)(ws + OFF_INT);
  const float* cs = ws + OFF_CS;
  int tid = threadIdx.x;
  int wv = tid >> 6, lane = tid & 63;
  {
    int half = lane >> 5, l32 = lane & 31;
    int bk = wv * 2 + half;                 // 16 waves x 2 halves = 32 beams
    float tv[4]; int ti[4];
#pragma unroll
    for (int r = 0; r < 4; r++) { tv[r] = -FLT_MAX; ti[r] = 0x7fffffff; }
    float M = -FLT_MAX, ls = 0.f;
    for (int g = 0; g < 4; g++) {           // 4 groups x 4 chunks = 16 chunks/lane
      float4 pa[4], pb[4], pc[4];
      bool vv[4];
#pragma unroll
      for (int j = 0; j < 4; j++) {
        int c = l32 + 32 * (g * 4 + j);
        vv[j] = c < NVCH;
        const float* p = cs + ((size_t)c * BKn + bk) * 12;
        if (vv[j]) {
          pa[j] = *(const float4*)p;        // {m, se, ov0, ov1}
          pb[j] = *(const float4*)(p + 4);  // {ov2, ov3, oi0, oi1}
          pc[j] = *(const float4*)(p + 8);  // {oi2, oi3, -, -}
        }
      }
#pragma unroll
      for (int j = 0; j < 4; j++) {
        if (vv[j]) {
          float cm = pa[j].x, csum = pa[j].y;
          if (cm > M) { ls *= expf(M - cm); M = cm; }   // ls==0 when M==-inf
          ls += csum * expf(cm - M);
          ins4(pa[j].z, __float_as_int(pb[j].z), tv, ti);
          ins4(pa[j].w, __float_as_int(pb[j].w), tv, ti);
          ins4(pb[j].x, __float_as_int(pc[j].x), tv, ti);
          ins4(pb[j].y, __float_as_int(pc[j].y), tv, ti);
        }
      }
    }
    for (int off = 16; off; off >>= 1) {
      float Mo = __shfl_xor(M, off), lso = __shfl_xor(ls, off);
      float Mn = fmaxf(M, Mo);
      ls = ls * expf(M - Mn) + lso * expf(Mo - Mn);
      M = Mn;
    }
    float lse = M + logf(ls);
    float ov[4]; int oi[4];
    merge_top4<16>(tv, ti, ov, oi);
    if (l32 == 0) {
#pragma unroll
      for (int r = 0; r < 4; r++) {
        bt_s[bk][r] = lse - ov[r];
        bt_s[bk][4 + r] = __int_as_float(oi[r]);
      }
    }
  }
  __syncthreads();
  if (tid < Bb) {
    int b = tid;
    int st = wsi[ISTOP + b];
    float sc[4];
#pragma unroll
    for (int k = 0; k < 4; k++) sc[k] = ws[OFF_SC + b * 4 + k];
    float cval[16]; int ctok[16];
#pragma unroll
    for (int kb = 0; kb < 4; kb++)
#pragma unroll
      for (int r = 0; r < 4; r++) {
        cval[kb * 4 + r] = bt_s[b * 4 + kb][r] + sc[kb];
        ctok[kb * 4 + r] = __float_as_int(bt_s[b * 4 + kb][4 + r]);
      }
    float selS[4]; int selW[4], prevK[4];
    int usedMask = 0;
#pragma unroll
    for (int r = 0; r < 4; r++) {
      int best = -1; float bv = FLT_MAX;
#pragma unroll
      for (int t = 0; t < 16; t++) {
        if (!((usedMask >> t) & 1) && cval[t] < bv) { bv = cval[t]; best = t; }
      }
      usedMask |= 1 << best;
      int tok = 0;
#pragma unroll
      for (int t = 0; t < 16; t++) if (t == best) tok = ctok[t];   // no runtime index
      selS[r] = bv; selW[r] = tok; prevK[r] = best >> 2;
    }
    bool eos[4];
#pragma unroll
    for (int r = 0; r < 4; r++) eos[r] = (selW[r] == EOSt);
    bool first = eos[0] && !st;
#pragma unroll
    for (int r = 0; r < 4; r++) if (eos[r] && !first && !st) selS[r] = EOSSf;
#pragma unroll
    for (int k = 0; k < 4; k++) {
      int tok = st ? PADt : (first ? EOSt : selW[k]);
      int pb  = st ? k : prevK[k];
      s_tok[b * 4 + k] = tok;
      s_prevb[b * 4 + k] = pb;
      if (!st) { ws[OFF_SC + b * 4 + k] = selS[k]; wsi[IW + b * 4 + k] = selW[k]; }
      wsi[IPREV + b * 4 + k] = prevK[k];
    }
    wsi[ISTOP + b] = (st || first) ? 1 : 0;
  }
  __syncthreads();
  if (tid < 512) {
    const int* br = wsi + (((step & 1) == 0) ? IBUFA : IBUFB);
    int* bw = wsi + (((step & 1) == 0) ? IBUFB : IBUFA);
    int bkk = tid >> 4, t = tid & 15;
    int pb = s_prevb[bkk];
    int src = ((bkk & ~3) | pb) * Tt + t;
    int val = br[src];
    if (t == step) val = s_tok[bkk];
    bw[tid] = val;
  }
}

// Output read as float32 by harness: tokens as float values, scores as floats.
__global__ __launch_bounds__(256) void outK(const float* __restrict__ ws,
                                            float* __restrict__ out) {
  const int* wsi = (const int*)(ws + OFF_INT);
  int g = blockIdx.x * 256 + threadIdx.x;
  if (g < Bb * Kk * Tt) {
    out[g] = (float)wsi[IBUFA + g];               // final buf in A after 16 steps
  } else if (g < Bb * Kk * Tt + BKn) {
    out[g] = ws[OFF_SC + (g - Bb * Kk * Tt)];
  }
}

} // namespace

extern "C" void kernel_launch(void* const* d_in, const int* in_sizes, int n_in,
                              void* d_out, int out_size, void* d_ws, size_t ws_size,
                              hipStream_t stream) {
  (void)in_sizes; (void)n_in; (void)out_size; (void)ws_size;
  const int*   words = (const int*)d_in[0];
  const float* h0 = (const float*)d_in[1];
  const float* c0 = (const float*)d_in[2];
  const float* E  = (const float*)d_in[3];
  const float* Wx = (const float*)d_in[4];
  const float* Wh = (const float*)d_in[5];
  const float* bv = (const float*)d_in[6];
  const float* Wo = (const float*)d_in[7];
  const float* bo = (const float*)d_in[8];
  float* ws = (float*)d_ws;
  float* hTn = ws + OFF_HTN;
  float* cb0 = ws + OFF_CB0;
  float* cb1 = ws + OFF_CB1;
  float* Gp  = ws + OFF_GP;
  float* cs  = ws + OFF_CS;
  int*   wsi = (int*)(ws + OFF_INT);

  initK<<<129, 256, 0, stream>>>(words, h0, c0, ws);
  for (int j = 0; j < Tt; j++) {
    float* cPrev = (j & 1) ? cb1 : cb0;
    float* cNext = (j & 1) ? cb0 : cb1;
    gatesK<<<dim3(32, GDS), 256, 0, stream>>>(Wx, Wh, E, hTn, wsi, Gp);
    lstmK<<<dim3(32, 8), 256, 0, stream>>>(bv, Gp, cPrev, wsi, cNext, hTn);
    logitsAK<<<LNB, 256, 0, stream>>>(Wo, bo, hTn, cs);
    redSelK<<<1, 1024, 0, stream>>>(ws, j);
  }
  outK<<<3, 256, 0, stream>>>(ws, (float*)d_out);
}